// Round 4
// baseline (5972.255 us; speedup 1.0000x reference)
//
#include <hip/hip_runtime.h>
#include <hip/hip_bf16.h>

#define BATCH 1024
#define HD 256
#define MLEN 80
#define LPRE 60
#define LFWD 80
#define KIN 32
#define KOUT 16

typedef unsigned short bf16_t;
typedef __attribute__((ext_vector_type(8))) short bf16x8;
typedef __attribute__((ext_vector_type(4))) float f32x4;
typedef __attribute__((ext_vector_type(4))) unsigned u32x4;

#define MFMA __builtin_amdgcn_mfma_f32_16x16x32_bf16

__device__ __forceinline__ float bf2f(bf16_t v){ return __uint_as_float(((unsigned)v)<<16); }
__device__ __forceinline__ bf16_t f2bf(float f){
    unsigned u = __float_as_uint(f);
    return (bf16_t)((u + 0x7FFFu + ((u>>16)&1u)) >> 16);
}
__device__ __forceinline__ unsigned pack2(float lo, float hi){
    return (unsigned)f2bf(lo) | ((unsigned)f2bf(hi)<<16);
}
__device__ __forceinline__ float bflo(unsigned d){ return __uint_as_float(d<<16); }
__device__ __forceinline__ float bfhi(unsigned d){ return __uint_as_float(d & 0xffff0000u); }
__device__ __forceinline__ float sigm(float x){ return 1.0f/(1.0f+__expf(-x)); }

// Packed-B byte offsets inside a GRU weight pack (4 N-groups):
// r:[0,262144) z:[262144,524288) in:[524288,655360) hn:[655360,786432)
#define OFF_Z  262144
#define OFF_IN 524288
#define OFF_HN 655360

// ---------------------------------------------------------------------------
// Pack GRU weights: B[k][n] fragment-tiled bf16. grid 192x256 (one 16B chunk/thread)
// ---------------------------------------------------------------------------
__global__ void pack_gru(const float* __restrict__ Wih, const float* __restrict__ Whh,
                         bf16_t* __restrict__ dst)
{
    int T = blockIdx.x*256 + threadIdx.x;   // < 49152
    int grp, local;
    if (T < 16384){ grp=0; local=T; }
    else if (T < 32768){ grp=1; local=T-16384; }
    else if (T < 40960){ grp=2; local=T-32768; }
    else { grp=3; local=T-40960; }
    int nkt = (grp<2)?16:8;
    int nt  = local / (nkt*64);
    int rem = local - nt*(nkt*64);
    int kt  = rem >> 6;
    int l   = rem & 63;
    int n   = nt*16 + (l&15);
    int k0  = kt*32 + ((l>>4)<<3);
    unsigned w[4];
    #pragma unroll
    for (int h2=0; h2<4; h2++){
        float v[2];
        #pragma unroll
        for (int s=0; s<2; s++){
            int k = k0 + h2*2 + s;
            if (grp==0)      v[s] = (k<256)? Wih[(size_t)n*HD + k]       : Whh[(size_t)n*HD + (k-256)];
            else if (grp==1) v[s] = (k<256)? Wih[(size_t)(256+n)*HD + k] : Whh[(size_t)(256+n)*HD + (k-256)];
            else if (grp==2) v[s] = Wih[(size_t)(512+n)*HD + k];
            else             v[s] = Whh[(size_t)(512+n)*HD + k];
        }
        w[h2] = pack2(v[0], v[1]);
    }
    uint4 u = {w[0],w[1],w[2],w[3]};
    *(uint4*)((char*)dst + (size_t)T*16) = u;
}

// ---------------------------------------------------------------------------
// Pack K=512,N=256 B from W[256][512] (combW): B[k][n]=W[n][k]. grid 64x256
// ---------------------------------------------------------------------------
__global__ void pack_B512(const float* __restrict__ W, bf16_t* __restrict__ dst)
{
    int T = blockIdx.x*256 + threadIdx.x;   // < 16384
    int nt = T >> 10, kt = (T>>6)&15, l = T&63;
    int n = nt*16 + (l&15);
    int k0 = kt*32 + ((l>>4)<<3);
    unsigned w[4];
    #pragma unroll
    for (int h2=0; h2<4; h2++)
        w[h2] = pack2(W[(size_t)n*512 + k0+h2*2], W[(size_t)n*512 + k0+h2*2+1]);
    uint4 u = {w[0],w[1],w[2],w[3]};
    *(uint4*)((char*)dst + (size_t)T*16) = u;
}

// ---------------------------------------------------------------------------
// Wfuse[k][n] = sum_o dembW[n][o]*outW[o][k]; e_bias[n]=dembB[n]+sum_o outB[o]*dembW[n][o]
// grid 257x256
// ---------------------------------------------------------------------------
__global__ void wfuse_kernel(const float* __restrict__ dembW, const float* __restrict__ dembB,
                             const float* __restrict__ outW, const float* __restrict__ outB,
                             float* __restrict__ Wfuse, float* __restrict__ ebias)
{
    int T = blockIdx.x*256 + threadIdx.x;
    if (T < 65536){
        int k = T >> 8, n = T & 255;
        float acc = 0.f;
        #pragma unroll
        for (int o=0;o<16;o++) acc += dembW[(size_t)n*48 + o]*outW[(size_t)o*HD + k];
        Wfuse[(size_t)k*HD + n] = acc;
    } else if (T < 65792){
        int n = T - 65536;
        float acc = dembB[n];
        #pragma unroll
        for (int o=0;o<16;o++) acc += outB[o]*dembW[(size_t)n*48 + o];
        ebias[n] = acc;
    }
}

// ---------------------------------------------------------------------------
// Pack B_e [K=288][N=256]: kt<8 -> Wfuse[k][n]; kt==8 -> dembW[n][16+k']. grid 36x256
// ---------------------------------------------------------------------------
__global__ void pack_e(const float* __restrict__ Wfuse, const float* __restrict__ dembW,
                       bf16_t* __restrict__ dst)
{
    int T = blockIdx.x*256 + threadIdx.x;   // < 9216
    int nt = T/576, rem = T - nt*576;
    int kt = rem >> 6, l = rem & 63;
    int n = nt*16 + (l&15);
    int k0 = kt*32 + ((l>>4)<<3);
    unsigned w[4];
    #pragma unroll
    for (int h2=0; h2<4; h2++){
        float v[2];
        #pragma unroll
        for (int s=0;s<2;s++){
            int k = k0 + h2*2 + s;
            v[s] = (kt<8)? Wfuse[(size_t)k*HD + n] : dembW[(size_t)n*48 + 16 + (k-256)];
        }
        w[h2] = pack2(v[0], v[1]);
    }
    uint4 u = {w[0],w[1],w[2],w[3]};
    *(uint4*)((char*)dst + (size_t)T*16) = u;
}

// ---------------------------------------------------------------------------
// Pack logits B (t>=1 and t==0 variants) + bias vectors. grid 24x256
// ---------------------------------------------------------------------------
__global__ void pack_logits(const float* __restrict__ Wfuse, const float* __restrict__ dembW,
                            const float* __restrict__ attW, const float* __restrict__ attB,
                            const float* __restrict__ dembB, const float* __restrict__ ebias,
                            bf16_t* __restrict__ BL, bf16_t* __restrict__ BL0,
                            float* __restrict__ lb, float* __restrict__ lb0)
{
    int T = blockIdx.x*256 + threadIdx.x;
    if (T < 5760){
        int variant = (T < 2880) ? 0 : 1;
        int local = variant ? (T-2880) : T;
        int nt = local/576, rem = local - nt*576;
        int kt = rem >> 6, l = rem & 63;
        int m  = nt*16 + (l&15);
        int k0 = kt*32 + ((l>>4)<<3);
        unsigned w[4];
        #pragma unroll
        for (int h2=0; h2<4; h2++){
            float v[2];
            for (int s=0;s<2;s++){
                int k = k0 + h2*2 + s;
                float acc;
                if (kt < 8){
                    if (variant == 0){
                        acc = attW[(size_t)m*512 + 256 + k];
                        for (int n=0;n<256;n++) acc += Wfuse[(size_t)k*HD + n]*attW[(size_t)m*512 + n];
                    } else {
                        acc = attW[(size_t)m*512 + 256 + k];
                    }
                } else {
                    int kp = k - 256;
                    acc = 0.f;
                    for (int n=0;n<256;n++) acc += dembW[(size_t)n*48 + 16 + kp]*attW[(size_t)m*512 + n];
                }
                v[s] = acc;
            }
            w[h2] = pack2(v[0], v[1]);
        }
        uint4 u = {w[0],w[1],w[2],w[3]};
        bf16_t* d = variant ? BL0 : BL;
        *(uint4*)((char*)d + (size_t)local*16) = u;
    } else if (T < 5840){
        int m = T - 5760;
        float acc = attB[m];
        for (int n=0;n<256;n++) acc += ebias[n]*attW[(size_t)m*512 + n];
        lb[m] = acc;
    } else if (T < 5920){
        int m = T - 5840;
        float acc = attB[m];
        for (int n=0;n<256;n++) acc += dembB[n]*attW[(size_t)m*512 + n];
        lb0[m] = acc;
    }
}

// ---------------------------------------------------------------------------
// Pack B_out [K=256][N=16] from outW[16][256]. grid 2x256 (512 chunks)
// ---------------------------------------------------------------------------
__global__ void pack_out(const float* __restrict__ outW, bf16_t* __restrict__ dst)
{
    int T = blockIdx.x*256 + threadIdx.x;   // < 512
    int kt = T >> 6, l = T & 63;
    int n  = l & 15;
    int k0 = kt*32 + ((l>>4)<<3);
    unsigned w[4];
    #pragma unroll
    for (int h2=0; h2<4; h2++)
        w[h2] = pack2(outW[(size_t)n*HD + k0+h2*2], outW[(size_t)n*HD + k0+h2*2+1]);
    uint4 u = {w[0],w[1],w[2],w[3]};
    *(uint4*)((char*)dst + (size_t)T*16) = u;
}

// ---------------------------------------------------------------------------
// All 60 encoder embeddings -> bf16. grid (64,60)x256
// ---------------------------------------------------------------------------
__global__ __launch_bounds__(256) void emb_kernel(
    const float* __restrict__ px, const float* __restrict__ py,
    const float* __restrict__ embW, const float* __restrict__ embB,
    bf16_t* __restrict__ emb)
{
    __shared__ float Ws[256*49];
    __shared__ float xy[16][48];
    __shared__ float bs[256];
    int t = blockIdx.y, b0 = blockIdx.x*16, tid = threadIdx.x;
    for (int i = tid; i < 256*48; i += 256){ int n=i/48, k=i-n*48; Ws[n*49+k]=embW[i]; }
    bs[tid] = embB[tid];
    for (int i = tid; i < 16*48; i += 256){
        int r=i/48, k=i-r*48;
        xy[r][k] = (k<KIN)? px[((size_t)t*BATCH + b0+r)*KIN + k]
                          : py[((size_t)t*BATCH + b0+r)*KOUT + (k-KIN)];
    }
    __syncthreads();
    int n = tid;
    const float* w = &Ws[n*49];
    for (int r=0;r<16;r++){
        float acc = bs[n];
        #pragma unroll
        for (int k=0;k<48;k++) acc += xy[r][k]*w[k];
        emb[((size_t)t*BATCH + b0+r)*HD + n] = f2bf(acc);
    }
}

// fx f32 -> bf16. grid 1280x256, one 8-elem chunk/thread
__global__ void fxconv(const float* __restrict__ fx, bf16_t* __restrict__ dst)
{
    size_t i = (size_t)blockIdx.x*256 + threadIdx.x;
    const float4* s = (const float4*)(fx + i*8);
    float4 a = s[0], b = s[1];
    uint4 u = { pack2(a.x,a.y), pack2(a.z,a.w), pack2(b.x,b.y), pack2(b.z,b.w) };
    *(uint4*)(dst + i*8) = u;
}

// ---------------------------------------------------------------------------
// GRU MFMA + epilogue helpers (persistent kernel). 8 waves: wave handles
// jt = wave*2, wave*2+1 (16 j-tiles x 16 cols = 256 outputs).
// ---------------------------------------------------------------------------
__device__ __forceinline__ void gru_mfma(
    const bf16_t (*Xb)[264], const bf16_t (*Hb)[264],
    const char* bpc, int lane, int wave,
    f32x4 cr[2], f32x4 cz[2], f32x4 ci[2], f32x4 ch[2])
{
    size_t loff = (size_t)lane*16;
    const bf16_t* ar = &Xb[lane&15][(lane>>4)*8];
    const bf16_t* ah = &Hb[lane&15][(lane>>4)*8];
    #pragma unroll
    for (int u=0; u<2; u++){
        int jt = wave*2 + u;
        f32x4 xr={0,0,0,0}, xz={0,0,0,0}, xi={0,0,0,0}, xh={0,0,0,0};
        #pragma unroll
        for (int kt=0; kt<16; kt++){
            bf16x8 a = (kt<8)? *(const bf16x8*)(ar + kt*32)
                             : *(const bf16x8*)(ah + (kt-8)*32);
            bf16x8 br = *(const bf16x8*)(bpc + (size_t)(((jt<<4)+kt)<<10) + loff);
            bf16x8 bz = *(const bf16x8*)(bpc + OFF_Z + (size_t)(((jt<<4)+kt)<<10) + loff);
            xr = MFMA(a, br, xr, 0,0,0);
            xz = MFMA(a, bz, xz, 0,0,0);
            if (kt < 8){
                bf16x8 bi = *(const bf16x8*)(bpc + OFF_IN + (size_t)(((jt<<3)+kt)<<10) + loff);
                xi = MFMA(a, bi, xi, 0,0,0);
            } else {
                bf16x8 bh = *(const bf16x8*)(bpc + OFF_HN + (size_t)(((jt<<3)+kt-8)<<10) + loff);
                xh = MFMA(a, bh, xh, 0,0,0);
            }
        }
        cr[u]=xr; cz[u]=xz; ci[u]=xi; ch[u]=xh;
    }
}

__device__ __forceinline__ void gru_epi(
    bf16_t (*Hb)[264], float (*Hf)[260],
    const float* __restrict__ bih, const float* __restrict__ bhh,
    int lane, int wave,
    const f32x4 cr[2], const f32x4 cz[2], const f32x4 ci[2], const f32x4 ch[2])
{
    #pragma unroll
    for (int u=0; u<2; u++){
        int jt = wave*2 + u;
        int j = (jt<<4) + (lane&15);
        float b_r = bih[j] + bhh[j];
        float b_z = bih[256+j] + bhh[256+j];
        float b_i = bih[512+j], b_h = bhh[512+j];
        #pragma unroll
        for (int q=0;q<4;q++){
            int r = ((lane>>4)<<2) + q;
            float rv = sigm(cr[u][q] + b_r);
            float zv = sigm(cz[u][q] + b_z);
            float nv = tanhf(ci[u][q] + b_i + rv*(ch[u][q] + b_h));
            float h2 = (1.0f - zv)*nv + zv*Hf[r][j];
            Hf[r][j] = h2;
            Hb[r][j] = f2bf(h2);
        }
    }
}

// ---------------------------------------------------------------------------
// Persistent seq2seq: 64 WGs x 512 threads; WG owns batch rows b0..b0+15.
// Everything is batch-local: h lives in LDS; no inter-WG communication.
// v4 changes vs round-1: (1) ctx reads ENC2 via NONTEMPORAL loads, 15-deep
// unrolled (no L2 pollution -> decode weights stay L2-resident; 4 latency
// windows instead of 15); (2) ENC2 writes + EMB/FX staging loads nontemporal.
// ---------------------------------------------------------------------------
__global__ __launch_bounds__(512, 2) void seq2seq_persist(
    const bf16_t* __restrict__ EMB,      // [60][B][H] bf16 (encoder embeddings)
    const bf16_t* __restrict__ FXB,      // [80][B][KIN] bf16
    bf16_t* __restrict__ ENC2,           // [B][60][H] bf16 (per-WG contiguous)
    const bf16_t* __restrict__ Bge, const bf16_t* __restrict__ Bgd,
    const bf16_t* __restrict__ Bcmb, const bf16_t* __restrict__ Be,
    const bf16_t* __restrict__ Bl, const bf16_t* __restrict__ Bl0,
    const bf16_t* __restrict__ Bout,
    const float* __restrict__ ebih, const float* __restrict__ ebhh,
    const float* __restrict__ dbih, const float* __restrict__ dbhh,
    const float* __restrict__ ebias, const float* __restrict__ dembB,
    const float* __restrict__ lb, const float* __restrict__ lb0,
    const float* __restrict__ combB, const float* __restrict__ outB,
    float* __restrict__ out)
{
    __shared__ __align__(16) bf16_t Hb[16][264];    // h bf16 (stride 528B = 33*16)
    __shared__ __align__(16) bf16_t Xb[16][264];    // emb_t (enc) / g (dec)
    __shared__ __align__(16) bf16_t Eb[16][264];    // e
    __shared__ __align__(16) bf16_t Cbuf[16][264];  // ctx
    __shared__ __align__(16) bf16_t FXb[16][40];    // fx_t (stride 80B = 5*16)
    __shared__ float Hf[16][260];                   // h f32
    __shared__ float awL[16][84];                   // logits -> aw

    int tid  = threadIdx.x;
    int lane = tid & 63, wave = tid >> 6;
    int b0   = blockIdx.x * 16;
    size_t loff = (size_t)lane*16;

    // init: zero h, load emb t=0
    for (int i = tid; i < 16*264; i += 512) ((bf16_t*)Hb)[i] = 0;
    for (int i = tid; i < 16*260; i += 512) ((float*)Hf)[i] = 0.f;
    {
        int r = tid >> 5, c0 = (tid & 31) * 8;
        u32x4 v = __builtin_nontemporal_load((const u32x4*)&EMB[((size_t)0*BATCH + b0+r)*HD + c0]);
        *(u32x4*)&Xb[r][c0] = v;
    }
    __syncthreads();

    // ================= encoder =================
    #pragma unroll 1
    for (int t = 0; t < LPRE; t++){
        f32x4 cr[2], cz[2], ci[2], ch[2];
        gru_mfma(Xb, Hb, (const char*)Bge, lane, wave, cr, cz, ci, ch);
        __syncthreads();
        gru_epi(Hb, Hf, ebih, ebhh, lane, wave, cr, cz, ci, ch);
        __syncthreads();
        // copy phase: ENC2[b][t][:] <- Hb (nt store); stage next emb / first fx
        {
            int r = tid >> 5, c0 = (tid & 31) * 8;
            u32x4 hv = *(const u32x4*)&Hb[r][c0];
            __builtin_nontemporal_store(hv, (u32x4*)(ENC2 + ((size_t)(b0+r)*LPRE + t)*HD + c0));
            if (t+1 < LPRE){
                u32x4 ev = __builtin_nontemporal_load((const u32x4*)&EMB[((size_t)(t+1)*BATCH + b0+r)*HD + c0]);
                *(u32x4*)&Xb[r][c0] = ev;
            }
        }
        if (t == LPRE-1 && tid < 64){
            int r = tid >> 2, c0 = (tid & 3) * 8;
            u32x4 fv = __builtin_nontemporal_load((const u32x4*)&FXB[((size_t)0*BATCH + b0+r)*KIN + c0]);
            *(u32x4*)&FXb[r][c0] = fv;
        }
        __syncthreads();
    }

    // ================= decoder =================
    #pragma unroll 1
    for (int t = 0; t < LFWD; t++){
        const char*  BLc = (const char*)(t ? Bl : Bl0);
        const float* lbp = t ? lb : lb0;
        const float* ebp = t ? ebias : dembB;
        int ke0 = t ? 0 : 8;

        // ---- P1: e (units 0..15) + logits (units 16..20), K = [h | fx] ----
        const bf16_t* ahb = &Hb[lane&15][(lane>>4)*8];
        const bf16_t* afx = &FXb[lane&15][(lane>>4)*8];
        for (int u = wave; u < 21; u += 8){
            int isl = (u >= 16);
            int nt  = isl ? (u - 16) : u;
            const char* bb = isl ? BLc : (const char*)Be;
            int k0 = isl ? 0 : ke0;
            f32x4 c = {0,0,0,0};
            if (k0 == 0){
                #pragma unroll
                for (int kt=0; kt<8; kt++){
                    bf16x8 a = *(const bf16x8*)(ahb + kt*32);
                    bf16x8 b = *(const bf16x8*)(bb + (size_t)((nt*9+kt)<<10) + loff);
                    c = MFMA(a, b, c, 0,0,0);
                }
            }
            {
                bf16x8 a = *(const bf16x8*)afx;
                bf16x8 b = *(const bf16x8*)(bb + (size_t)((nt*9+8)<<10) + loff);
                c = MFMA(a, b, c, 0,0,0);
            }
            if (!isl){
                int n = (nt<<4) + (lane&15);
                float bbn = ebp[n];
                #pragma unroll
                for (int q=0;q<4;q++) Eb[((lane>>4)<<2)+q][n] = f2bf(c[q] + bbn);
            } else {
                int m = (nt<<4) + (lane&15);
                float bbm = lbp[m];
                #pragma unroll
                for (int q=0;q<4;q++) awL[((lane>>4)<<2)+q][m] = c[q] + bbm;
            }
        }
        __syncthreads();

        // ---- P2: softmax over awL rows (16 threads/row, shuffle reduce) ----
        if (tid < 256){
            int r2 = tid >> 4, l2 = tid & 15;
            float vmax = -1e30f;
            for (int m=l2; m<80; m+=16) vmax = fmaxf(vmax, awL[r2][m]);
            #pragma unroll
            for (int k=1; k<16; k<<=1) vmax = fmaxf(vmax, __shfl_xor(vmax, k, 16));
            float ps = 0.f;
            for (int m=l2; m<80; m+=16){ float v = __expf(awL[r2][m]-vmax); awL[r2][m]=v; ps += v; }
            #pragma unroll
            for (int k=1; k<16; k<<=1) ps += __shfl_xor(ps, k, 16);
            float inv = 1.0f/ps;
            for (int m=l2; m<80; m+=16) awL[r2][m] *= inv;
        }
        __syncthreads();

        // ---- P3: ctx[r][c] = sum_m aw[r][m]*enc[b][m][c] (nt loads, 15-deep) ----
        {
            int r = tid >> 5, c0 = (tid & 31) * 8;
            float acc[8];
            #pragma unroll
            for (int i=0;i<8;i++) acc[i] = 0.f;
            const bf16_t* bp = ENC2 + (size_t)(b0+r)*LPRE*HD + c0;
            #pragma unroll
            for (int mb=0; mb<LPRE; mb+=15){
                u32x4 v[15];
                #pragma unroll
                for (int i=0;i<15;i++)
                    v[i] = __builtin_nontemporal_load((const u32x4*)(bp + (size_t)(mb+i)*HD));
                #pragma unroll
                for (int i=0;i<15;i++){
                    float w = awL[r][mb+i];
                    acc[0] = fmaf(w, bflo(v[i][0]), acc[0]);
                    acc[1] = fmaf(w, bfhi(v[i][0]), acc[1]);
                    acc[2] = fmaf(w, bflo(v[i][1]), acc[2]);
                    acc[3] = fmaf(w, bfhi(v[i][1]), acc[3]);
                    acc[4] = fmaf(w, bflo(v[i][2]), acc[4]);
                    acc[5] = fmaf(w, bfhi(v[i][2]), acc[5]);
                    acc[6] = fmaf(w, bflo(v[i][3]), acc[6]);
                    acc[7] = fmaf(w, bfhi(v[i][3]), acc[7]);
                }
            }
            uint4 ov;
            ov.x = pack2(acc[0],acc[1]); ov.y = pack2(acc[2],acc[3]);
            ov.z = pack2(acc[4],acc[5]); ov.w = pack2(acc[6],acc[7]);
            *(uint4*)&Cbuf[r][c0] = ov;
        }
        __syncthreads();

        // ---- P4: g = tanh([e|ctx]@Bcmb + combB) -> Xb ----
        {
            const bf16_t* ae = &Eb[lane&15][(lane>>4)*8];
            const bf16_t* ac = &Cbuf[lane&15][(lane>>4)*8];
            #pragma unroll
            for (int u=0; u<2; u++){
                int nt = wave*2 + u;
                f32x4 c = {0,0,0,0};
                #pragma unroll
                for (int kt=0; kt<16; kt++){
                    bf16x8 a = (kt<8)? *(const bf16x8*)(ae + kt*32)
                                     : *(const bf16x8*)(ac + (kt-8)*32);
                    bf16x8 b = *(const bf16x8*)((const char*)Bcmb + (size_t)(((nt<<4)+kt)<<10) + loff);
                    c = MFMA(a, b, c, 0,0,0);
                }
                int n = (nt<<4) + (lane&15);
                float bbn = combB[n];
                #pragma unroll
                for (int q=0;q<4;q++) Xb[((lane>>4)<<2)+q][n] = f2bf(tanhf(c[q] + bbn));
            }
        }
        __syncthreads();

        // ---- P5: GRU (dec) ----
        {
            f32x4 cr[2], cz[2], ci[2], ch[2];
            gru_mfma(Xb, Hb, (const char*)Bgd, lane, wave, cr, cz, ci, ch);
            __syncthreads();
            gru_epi(Hb, Hf, dbih, dbhh, lane, wave, cr, cz, ci, ch);
        }
        __syncthreads();

        // ---- P6: ys_t = h@outW^T + outB (wave 0); stage fx_{t+1} (wave 7) ----
        if (wave == 0){
            f32x4 c = {0,0,0,0};
            #pragma unroll
            for (int kt=0; kt<8; kt++){
                bf16x8 a = *(const bf16x8*)(ahb + kt*32);
                bf16x8 b = *(const bf16x8*)((const char*)Bout + (size_t)(kt<<10) + loff);
                c = MFMA(a, b, c, 0,0,0);
            }
            int o = lane & 15;
            float bo = outB[o];
            #pragma unroll
            for (int q=0;q<4;q++){
                int r = ((lane>>4)<<2) + q;
                out[((size_t)t*BATCH + b0+r)*KOUT + o] = c[q] + bo;
            }
        }
        if (t+1 < LFWD && wave == 7){
            int r = (tid-448) >> 2, c0 = (tid & 3) * 8;
            u32x4 fv = __builtin_nontemporal_load((const u32x4*)&FXB[((size_t)(t+1)*BATCH + b0+r)*KIN + c0]);
            *(u32x4*)&FXb[r][c0] = fv;
        }
        __syncthreads();
    }
}

// ---------------------------------------------------------------------------
extern "C" void kernel_launch(void* const* d_in, const int* in_sizes, int n_in,
                              void* d_out, int out_size, void* d_ws, size_t ws_size,
                              hipStream_t stream) {
    const float* pre_x    = (const float*)d_in[0];
    const float* pre_y    = (const float*)d_in[1];
    const float* fwd_x    = (const float*)d_in[2];
    const float* enc_embW = (const float*)d_in[3];
    const float* enc_embB = (const float*)d_in[4];
    const float* enc_Wih  = (const float*)d_in[5];
    const float* enc_Whh  = (const float*)d_in[6];
    const float* enc_bih  = (const float*)d_in[7];
    const float* enc_bhh  = (const float*)d_in[8];
    const float* dec_embW = (const float*)d_in[9];
    const float* dec_embB = (const float*)d_in[10];
    const float* attn_W   = (const float*)d_in[11];
    const float* attn_b   = (const float*)d_in[12];
    const float* comb_W   = (const float*)d_in[13];
    const float* comb_b   = (const float*)d_in[14];
    const float* dec_Wih  = (const float*)d_in[15];
    const float* dec_Whh  = (const float*)d_in[16];
    const float* dec_bih  = (const float*)d_in[17];
    const float* dec_bhh  = (const float*)d_in[18];
    const float* out_W    = (const float*)d_in[19];
    const float* out_b    = (const float*)d_in[20];
    float* out = (float*)d_out;

    char* ws = (char*)d_ws;
    size_t o = 0;
    auto alloc = [&](size_t bytes)->char*{
        char* p = ws + o; o = (o + bytes + 255) & ~(size_t)255; return p;
    };
    bf16_t* EMB     = (bf16_t*)alloc((size_t)LPRE*BATCH*HD*2);      // 31.5 MB
    bf16_t* ENC2    = (bf16_t*)alloc((size_t)BATCH*LPRE*HD*2);      // 31.5 MB [b][t][c]
    bf16_t* FXB     = (bf16_t*)alloc((size_t)LFWD*BATCH*KIN*2);     // 5.2 MB
    float*  WFUSE   = (float*) alloc((size_t)256*256*4);
    float*  EBIAS   = (float*) alloc(256*4);
    float*  LB      = (float*) alloc(80*4);
    float*  LB0     = (float*) alloc(80*4);
    bf16_t* PACK_ENC = (bf16_t*)alloc(786432);
    bf16_t* PACK_DEC = (bf16_t*)alloc(786432);
    bf16_t* PACK_CMB = (bf16_t*)alloc(262144);
    bf16_t* PACK_E   = (bf16_t*)alloc(147456);
    bf16_t* PACK_BL  = (bf16_t*)alloc(46080);
    bf16_t* PACK_BL0 = (bf16_t*)alloc(46080);
    bf16_t* PACK_OUT = (bf16_t*)alloc(8192);

    dim3 blk(256);
    // ---- prep (one-time, stream-ordered before the persistent kernel) ----
    emb_kernel<<<dim3(64,60), blk, 0, stream>>>(pre_x, pre_y, enc_embW, enc_embB, EMB);
    fxconv<<<dim3(1280), blk, 0, stream>>>(fwd_x, FXB);
    pack_gru<<<dim3(192), blk, 0, stream>>>(enc_Wih, enc_Whh, PACK_ENC);
    pack_gru<<<dim3(192), blk, 0, stream>>>(dec_Wih, dec_Whh, PACK_DEC);
    pack_B512<<<dim3(64), blk, 0, stream>>>(comb_W, PACK_CMB);
    wfuse_kernel<<<dim3(257), blk, 0, stream>>>(dec_embW, dec_embB, out_W, out_b, WFUSE, EBIAS);
    pack_e<<<dim3(36), blk, 0, stream>>>(WFUSE, dec_embW, PACK_E);
    pack_logits<<<dim3(24), blk, 0, stream>>>(WFUSE, dec_embW, attn_W, attn_b, dec_embB,
                                              EBIAS, PACK_BL, PACK_BL0, LB, LB0);
    pack_out<<<dim3(2), blk, 0, stream>>>(out_W, PACK_OUT);

    // ---- the whole recurrence in ONE kernel: 64 WGs x 512 thr, batch-local ----
    seq2seq_persist<<<dim3(64), dim3(512), 0, stream>>>(
        EMB, FXB, ENC2,
        PACK_ENC, PACK_DEC, PACK_CMB, PACK_E, PACK_BL, PACK_BL0, PACK_OUT,
        enc_bih, enc_bhh, dec_bih, dec_bhh,
        EBIAS, dec_embB, LB, LB0, comb_b, out_b, out);
}

// Round 5
// 2480.332 us; speedup vs baseline: 2.4078x; 2.4078x over previous
//
#include <hip/hip_runtime.h>
#include <hip/hip_bf16.h>

#define BATCH 1024
#define HD 256
#define MLEN 80
#define LPRE 60
#define LFWD 80
#define KIN 32
#define KOUT 16

typedef unsigned short bf16_t;
typedef __attribute__((ext_vector_type(8))) short bf16x8;
typedef __attribute__((ext_vector_type(4))) float f32x4;
typedef __attribute__((ext_vector_type(4))) unsigned u32x4;

#define MFMA __builtin_amdgcn_mfma_f32_16x16x32_bf16

__device__ __forceinline__ float bf2f(bf16_t v){ return __uint_as_float(((unsigned)v)<<16); }
__device__ __forceinline__ bf16_t f2bf(float f){
    unsigned u = __float_as_uint(f);
    return (bf16_t)((u + 0x7FFFu + ((u>>16)&1u)) >> 16);
}
__device__ __forceinline__ unsigned pack2(float lo, float hi){
    return (unsigned)f2bf(lo) | ((unsigned)f2bf(hi)<<16);
}
__device__ __forceinline__ float bflo(unsigned d){ return __uint_as_float(d<<16); }
__device__ __forceinline__ float bfhi(unsigned d){ return __uint_as_float(d & 0xffff0000u); }
__device__ __forceinline__ float sigm(float x){ return 1.0f/(1.0f+__expf(-x)); }

// Packed-B byte offsets inside a GRU weight pack (4 N-groups):
// r:[0,262144) z:[262144,524288) in:[524288,655360) hn:[655360,786432)
#define OFF_Z  262144
#define OFF_IN 524288
#define OFF_HN 655360

// ---------------------------------------------------------------------------
// Pack GRU weights: B[k][n] fragment-tiled bf16. grid 192x256 (one 16B chunk/thread)
// ---------------------------------------------------------------------------
__global__ void pack_gru(const float* __restrict__ Wih, const float* __restrict__ Whh,
                         bf16_t* __restrict__ dst)
{
    int T = blockIdx.x*256 + threadIdx.x;   // < 49152
    int grp, local;
    if (T < 16384){ grp=0; local=T; }
    else if (T < 32768){ grp=1; local=T-16384; }
    else if (T < 40960){ grp=2; local=T-32768; }
    else { grp=3; local=T-40960; }
    int nkt = (grp<2)?16:8;
    int nt  = local / (nkt*64);
    int rem = local - nt*(nkt*64);
    int kt  = rem >> 6;
    int l   = rem & 63;
    int n   = nt*16 + (l&15);
    int k0  = kt*32 + ((l>>4)<<3);
    unsigned w[4];
    #pragma unroll
    for (int h2=0; h2<4; h2++){
        float v[2];
        #pragma unroll
        for (int s=0; s<2; s++){
            int k = k0 + h2*2 + s;
            if (grp==0)      v[s] = (k<256)? Wih[(size_t)n*HD + k]       : Whh[(size_t)n*HD + (k-256)];
            else if (grp==1) v[s] = (k<256)? Wih[(size_t)(256+n)*HD + k] : Whh[(size_t)(256+n)*HD + (k-256)];
            else if (grp==2) v[s] = Wih[(size_t)(512+n)*HD + k];
            else             v[s] = Whh[(size_t)(512+n)*HD + k];
        }
        w[h2] = pack2(v[0], v[1]);
    }
    uint4 u = {w[0],w[1],w[2],w[3]};
    *(uint4*)((char*)dst + (size_t)T*16) = u;
}

// ---------------------------------------------------------------------------
// Pack K=512,N=256 B from W[256][512] (combW): B[k][n]=W[n][k]. grid 64x256
// ---------------------------------------------------------------------------
__global__ void pack_B512(const float* __restrict__ W, bf16_t* __restrict__ dst)
{
    int T = blockIdx.x*256 + threadIdx.x;   // < 16384
    int nt = T >> 10, kt = (T>>6)&15, l = T&63;
    int n = nt*16 + (l&15);
    int k0 = kt*32 + ((l>>4)<<3);
    unsigned w[4];
    #pragma unroll
    for (int h2=0; h2<4; h2++)
        w[h2] = pack2(W[(size_t)n*512 + k0+h2*2], W[(size_t)n*512 + k0+h2*2+1]);
    uint4 u = {w[0],w[1],w[2],w[3]};
    *(uint4*)((char*)dst + (size_t)T*16) = u;
}

// ---------------------------------------------------------------------------
// Wfuse[k][n] = sum_o dembW[n][o]*outW[o][k]; e_bias[n]=dembB[n]+sum_o outB[o]*dembW[n][o]
// grid 257x256
// ---------------------------------------------------------------------------
__global__ void wfuse_kernel(const float* __restrict__ dembW, const float* __restrict__ dembB,
                             const float* __restrict__ outW, const float* __restrict__ outB,
                             float* __restrict__ Wfuse, float* __restrict__ ebias)
{
    int T = blockIdx.x*256 + threadIdx.x;
    if (T < 65536){
        int k = T >> 8, n = T & 255;
        float acc = 0.f;
        #pragma unroll
        for (int o=0;o<16;o++) acc += dembW[(size_t)n*48 + o]*outW[(size_t)o*HD + k];
        Wfuse[(size_t)k*HD + n] = acc;
    } else if (T < 65792){
        int n = T - 65536;
        float acc = dembB[n];
        #pragma unroll
        for (int o=0;o<16;o++) acc += outB[o]*dembW[(size_t)n*48 + o];
        ebias[n] = acc;
    }
}

// ---------------------------------------------------------------------------
// Pack B_e [K=288][N=256]: kt<8 -> Wfuse[k][n]; kt==8 -> dembW[n][16+k']. grid 36x256
// ---------------------------------------------------------------------------
__global__ void pack_e(const float* __restrict__ Wfuse, const float* __restrict__ dembW,
                       bf16_t* __restrict__ dst)
{
    int T = blockIdx.x*256 + threadIdx.x;   // < 9216
    int nt = T/576, rem = T - nt*576;
    int kt = rem >> 6, l = rem & 63;
    int n = nt*16 + (l&15);
    int k0 = kt*32 + ((l>>4)<<3);
    unsigned w[4];
    #pragma unroll
    for (int h2=0; h2<4; h2++){
        float v[2];
        #pragma unroll
        for (int s=0;s<2;s++){
            int k = k0 + h2*2 + s;
            v[s] = (kt<8)? Wfuse[(size_t)k*HD + n] : dembW[(size_t)n*48 + 16 + (k-256)];
        }
        w[h2] = pack2(v[0], v[1]);
    }
    uint4 u = {w[0],w[1],w[2],w[3]};
    *(uint4*)((char*)dst + (size_t)T*16) = u;
}

// ---------------------------------------------------------------------------
// Pack logits B (t>=1 and t==0 variants) + bias vectors. grid 24x256
// ---------------------------------------------------------------------------
__global__ void pack_logits(const float* __restrict__ Wfuse, const float* __restrict__ dembW,
                            const float* __restrict__ attW, const float* __restrict__ attB,
                            const float* __restrict__ dembB, const float* __restrict__ ebias,
                            bf16_t* __restrict__ BL, bf16_t* __restrict__ BL0,
                            float* __restrict__ lb, float* __restrict__ lb0)
{
    int T = blockIdx.x*256 + threadIdx.x;
    if (T < 5760){
        int variant = (T < 2880) ? 0 : 1;
        int local = variant ? (T-2880) : T;
        int nt = local/576, rem = local - nt*576;
        int kt = rem >> 6, l = rem & 63;
        int m  = nt*16 + (l&15);
        int k0 = kt*32 + ((l>>4)<<3);
        unsigned w[4];
        #pragma unroll
        for (int h2=0; h2<4; h2++){
            float v[2];
            for (int s=0;s<2;s++){
                int k = k0 + h2*2 + s;
                float acc;
                if (kt < 8){
                    if (variant == 0){
                        acc = attW[(size_t)m*512 + 256 + k];
                        for (int n=0;n<256;n++) acc += Wfuse[(size_t)k*HD + n]*attW[(size_t)m*512 + n];
                    } else {
                        acc = attW[(size_t)m*512 + 256 + k];
                    }
                } else {
                    int kp = k - 256;
                    acc = 0.f;
                    for (int n=0;n<256;n++) acc += dembW[(size_t)n*48 + 16 + kp]*attW[(size_t)m*512 + n];
                }
                v[s] = acc;
            }
            w[h2] = pack2(v[0], v[1]);
        }
        uint4 u = {w[0],w[1],w[2],w[3]};
        bf16_t* d = variant ? BL0 : BL;
        *(uint4*)((char*)d + (size_t)local*16) = u;
    } else if (T < 5840){
        int m = T - 5760;
        float acc = attB[m];
        for (int n=0;n<256;n++) acc += ebias[n]*attW[(size_t)m*512 + n];
        lb[m] = acc;
    } else if (T < 5920){
        int m = T - 5840;
        float acc = attB[m];
        for (int n=0;n<256;n++) acc += dembB[n]*attW[(size_t)m*512 + n];
        lb0[m] = acc;
    }
}

// ---------------------------------------------------------------------------
// Pack B_out [K=256][N=16] from outW[16][256]. grid 2x256 (512 chunks)
// ---------------------------------------------------------------------------
__global__ void pack_out(const float* __restrict__ outW, bf16_t* __restrict__ dst)
{
    int T = blockIdx.x*256 + threadIdx.x;   // < 512
    int kt = T >> 6, l = T & 63;
    int n  = l & 15;
    int k0 = kt*32 + ((l>>4)<<3);
    unsigned w[4];
    #pragma unroll
    for (int h2=0; h2<4; h2++)
        w[h2] = pack2(outW[(size_t)n*HD + k0+h2*2], outW[(size_t)n*HD + k0+h2*2+1]);
    uint4 u = {w[0],w[1],w[2],w[3]};
    *(uint4*)((char*)dst + (size_t)T*16) = u;
}

// ---------------------------------------------------------------------------
// All 60 encoder embeddings -> bf16. grid (64,60)x256
// ---------------------------------------------------------------------------
__global__ __launch_bounds__(256) void emb_kernel(
    const float* __restrict__ px, const float* __restrict__ py,
    const float* __restrict__ embW, const float* __restrict__ embB,
    bf16_t* __restrict__ emb)
{
    __shared__ float Ws[256*49];
    __shared__ float xy[16][48];
    __shared__ float bs[256];
    int t = blockIdx.y, b0 = blockIdx.x*16, tid = threadIdx.x;
    for (int i = tid; i < 256*48; i += 256){ int n=i/48, k=i-n*48; Ws[n*49+k]=embW[i]; }
    bs[tid] = embB[tid];
    for (int i = tid; i < 16*48; i += 256){
        int r=i/48, k=i-r*48;
        xy[r][k] = (k<KIN)? px[((size_t)t*BATCH + b0+r)*KIN + k]
                          : py[((size_t)t*BATCH + b0+r)*KOUT + (k-KIN)];
    }
    __syncthreads();
    int n = tid;
    const float* w = &Ws[n*49];
    for (int r=0;r<16;r++){
        float acc = bs[n];
        #pragma unroll
        for (int k=0;k<48;k++) acc += xy[r][k]*w[k];
        emb[((size_t)t*BATCH + b0+r)*HD + n] = f2bf(acc);
    }
}

// fx f32 -> bf16. grid 1280x256, one 8-elem chunk/thread
__global__ void fxconv(const float* __restrict__ fx, bf16_t* __restrict__ dst)
{
    size_t i = (size_t)blockIdx.x*256 + threadIdx.x;
    const float4* s = (const float4*)(fx + i*8);
    float4 a = s[0], b = s[1];
    uint4 u = { pack2(a.x,a.y), pack2(a.z,a.w), pack2(b.x,b.y), pack2(b.z,b.w) };
    *(uint4*)(dst + i*8) = u;
}

// ---------------------------------------------------------------------------
// Fused GRU step (enc & dec): C[1024,768] = [A0|A1]@B_cat, GRU epilogue.
// grid (64,4)x256. A0 = emb_t or g, A1 = h bf16. extra_bf = enc_out[t] or dummy.
// ---------------------------------------------------------------------------
__global__ __launch_bounds__(256) void gru_step(
    const bf16_t* __restrict__ A0, const bf16_t* __restrict__ A1,
    const bf16_t* __restrict__ Bp,
    const float* __restrict__ bih, const float* __restrict__ bhh,
    const float* __restrict__ hprev, float* __restrict__ hnext,
    bf16_t* __restrict__ hnext_bf, bf16_t* __restrict__ extra_bf)
{
    __shared__ __align__(16) bf16_t As[16][520];
    int tid = threadIdx.x, b0 = blockIdx.x*16;
    for (int i = tid; i < 1024; i += 256){
        int r = i>>6, c = i&63;
        const bf16_t* src = (c<32)? (A0 + (size_t)(b0+r)*HD + c*8)
                                  : (A1 + (size_t)(b0+r)*HD + (c-32)*8);
        *(uint4*)&As[r][c*8] = *(const uint4*)src;
    }
    __syncthreads();
    int lane = tid & 63, wave = tid >> 6;
    int jt = blockIdx.y*4 + wave;
    const char* arow = (const char*)&As[lane&15][(lane>>4)*8];
    const char* bpc = (const char*)Bp;
    size_t loff = (size_t)lane*16;
    f32x4 cr={0,0,0,0}, cz={0,0,0,0}, ci={0,0,0,0}, ch={0,0,0,0};
    #pragma unroll
    for (int kt=0; kt<16; kt++){
        bf16x8 a  = *(const bf16x8*)(arow + kt*64);
        bf16x8 br = *(const bf16x8*)(bpc + (size_t)(((jt<<4)+kt)<<10) + loff);
        bf16x8 bz = *(const bf16x8*)(bpc + OFF_Z + (size_t)(((jt<<4)+kt)<<10) + loff);
        cr = MFMA(a, br, cr, 0,0,0);
        cz = MFMA(a, bz, cz, 0,0,0);
        if (kt < 8){
            bf16x8 bi = *(const bf16x8*)(bpc + OFF_IN + (size_t)(((jt<<3)+kt)<<10) + loff);
            ci = MFMA(a, bi, ci, 0,0,0);
        } else {
            bf16x8 bh = *(const bf16x8*)(bpc + OFF_HN + (size_t)(((jt<<3)+kt-8)<<10) + loff);
            ch = MFMA(a, bh, ch, 0,0,0);
        }
    }
    int j = (jt<<4) + (lane&15);
    float b_r = bih[j] + bhh[j];
    float b_z = bih[256+j] + bhh[256+j];
    float b_i = bih[512+j], b_h = bhh[512+j];
    #pragma unroll
    for (int q=0;q<4;q++){
        int b = b0 + ((lane>>4)<<2) + q;
        float rv = sigm(cr[q] + b_r);
        float zv = sigm(cz[q] + b_z);
        float nv = tanhf(ci[q] + b_i + rv*(ch[q] + b_h));
        float h2 = (1.0f - zv)*nv + zv*hprev[(size_t)b*HD + j];
        hnext[(size_t)b*HD + j] = h2;
        bf16_t hb = f2bf(h2);
        hnext_bf[(size_t)b*HD + j] = hb;
        extra_bf[(size_t)b*HD + j] = hb;
    }
}

// ---------------------------------------------------------------------------
// dec_front v5: 1024 threads (16 waves). One dispatch fusing
// e + logits + ys_{t-1} + softmax + ctx + comb.
// P1/P4 at 1 tile per wave (halved serial depth); ctx m-split across wave
// halves with 10-deep register prefetch issued before the staging barrier.
// ---------------------------------------------------------------------------
__global__ __launch_bounds__(1024) void dec_front(
    const bf16_t* __restrict__ hbf, const bf16_t* __restrict__ fxt,
    const bf16_t* __restrict__ enc_out,
    const bf16_t* __restrict__ Be, const bf16_t* __restrict__ BL,
    const bf16_t* __restrict__ Bcmb, const bf16_t* __restrict__ Bout,
    const float* __restrict__ ebp, const float* __restrict__ lbp,
    const float* __restrict__ combB, const float* __restrict__ outB,
    int t, bf16_t* __restrict__ g_out, float* __restrict__ out)
{
    __shared__ __align__(16) bf16_t As[16][296];   // [h(256) | fx(32)]
    __shared__ __align__(16) bf16_t Eb[16][264];   // e
    __shared__ __align__(16) bf16_t Cb[16][264];   // ctx
    __shared__ float awL[16][84];                  // logits -> aw
    __shared__ float Cpart[16][256];               // ctx partial (m 0..29)

    int tid = threadIdx.x, b0 = blockIdx.x*16;

    // ---- stage As ----
    if (tid < 576){
        int r = tid/36, c = tid - r*36;
        const bf16_t* src = (c<32)? (hbf + (size_t)(b0+r)*HD + c*8)
                                  : (fxt + (size_t)(b0+r)*KIN + (c-32)*8);
        *(uint4*)&As[r][c*8] = *(const uint4*)src;
    }

    // ---- ctx geometry + issue-early prefetch (independent of As/aw) ----
    int half = tid >> 9;              // 0: m 0..29, 1: m 30..59
    int u    = tid & 511;
    int cr_  = u >> 5;                // row 0..15
    int cc0  = (u & 31) * 8;          // col chunk
    const bf16_t* cbp = enc_out + ((size_t)(half*30)*BATCH + (b0+cr_))*HD + cc0;
    u32x4 pf[10];
    #pragma unroll
    for (int i=0;i<10;i++) pf[i] = *(const u32x4*)(cbp + (size_t)i*BATCH*HD);

    __syncthreads();

    int lane = tid & 63, wave = tid >> 6;     // wave 0..15
    const bf16_t* arow = &As[lane&15][(lane>>4)*8];
    size_t loff = (size_t)lane*16;
    int ke0 = t ? 0 : 8;

    // ---- P1: 22 MFMA tiles over 16 waves (1-2 tiles/wave) ----
    {   // e-tile n = wave
        f32x4 c = {0,0,0,0};
        for (int kt = ke0; kt < 9; kt++){
            bf16x8 a = *(const bf16x8*)(arow + kt*32);
            bf16x8 b = *(const bf16x8*)((const char*)Be + (size_t)((wave*9+kt)<<10) + loff);
            c = MFMA(a, b, c, 0,0,0);
        }
        int n = (wave<<4) + (lane&15);
        float bbn = ebp[n];
        #pragma unroll
        for (int q=0;q<4;q++) Eb[((lane>>4)<<2)+q][n] = f2bf(c[q] + bbn);
    }
    if (wave < 5){
        // logits tile nt = wave
        f32x4 c = {0,0,0,0};
        #pragma unroll
        for (int kt = 0; kt < 9; kt++){
            bf16x8 a = *(const bf16x8*)(arow + kt*32);
            bf16x8 b = *(const bf16x8*)((const char*)BL + (size_t)((wave*9+kt)<<10) + loff);
            c = MFMA(a, b, c, 0,0,0);
        }
        int m = (wave<<4) + (lane&15);
        float bbm = lbp[m];
        #pragma unroll
        for (int q=0;q<4;q++) awL[((lane>>4)<<2)+q][m] = c[q] + bbm;
    } else if (wave == 5 && t > 0){
        // ys[t-1] = h @ outW^T + outB
        f32x4 c = {0,0,0,0};
        #pragma unroll
        for (int kt = 0; kt < 8; kt++){
            bf16x8 a = *(const bf16x8*)(arow + kt*32);
            bf16x8 b = *(const bf16x8*)((const char*)Bout + (size_t)(kt<<10) + loff);
            c = MFMA(a, b, c, 0,0,0);
        }
        int o = lane & 15;
        float bo = outB[o];
        #pragma unroll
        for (int q=0;q<4;q++){
            int r = ((lane>>4)<<2) + q;
            out[((size_t)(t-1)*BATCH + b0+r)*KOUT + o] = c[q] + bo;
        }
    }
    __syncthreads();

    // ---- P2: softmax over awL rows (16 threads/row, shuffle reduce) ----
    if (tid < 256){
        int r2 = tid >> 4, l2 = tid & 15;
        float vmax = -1e30f;
        for (int m=l2; m<80; m+=16) vmax = fmaxf(vmax, awL[r2][m]);
        #pragma unroll
        for (int k=1; k<16; k<<=1) vmax = fmaxf(vmax, __shfl_xor(vmax, k, 16));
        float ps = 0.f;
        for (int m=l2; m<80; m+=16){ float v = __expf(awL[r2][m]-vmax); awL[r2][m]=v; ps += v; }
        #pragma unroll
        for (int k=1; k<16; k<<=1) ps += __shfl_xor(ps, k, 16);
        float inv = 1.0f/ps;
        for (int m=l2; m<80; m+=16) awL[r2][m] *= inv;
    }
    __syncthreads();

    // ---- P3a: partial ctx, each thread 30 m (10 prefetched) ----
    float acc[8];
    #pragma unroll
    for (int i=0;i<8;i++) acc[i] = 0.f;
    {
        const float* awr = &awL[cr_][half*30];
        #pragma unroll
        for (int i=0;i<10;i++){
            float w = awr[i];
            acc[0] = fmaf(w, bflo(pf[i][0]), acc[0]);
            acc[1] = fmaf(w, bfhi(pf[i][0]), acc[1]);
            acc[2] = fmaf(w, bflo(pf[i][1]), acc[2]);
            acc[3] = fmaf(w, bfhi(pf[i][1]), acc[3]);
            acc[4] = fmaf(w, bflo(pf[i][2]), acc[4]);
            acc[5] = fmaf(w, bfhi(pf[i][2]), acc[5]);
            acc[6] = fmaf(w, bflo(pf[i][3]), acc[6]);
            acc[7] = fmaf(w, bfhi(pf[i][3]), acc[7]);
        }
        #pragma unroll 5
        for (int i=10;i<30;i++){
            u32x4 v = *(const u32x4*)(cbp + (size_t)i*BATCH*HD);
            float w = awr[i];
            acc[0] = fmaf(w, bflo(v[0]), acc[0]);
            acc[1] = fmaf(w, bfhi(v[0]), acc[1]);
            acc[2] = fmaf(w, bflo(v[1]), acc[2]);
            acc[3] = fmaf(w, bfhi(v[1]), acc[3]);
            acc[4] = fmaf(w, bflo(v[2]), acc[4]);
            acc[5] = fmaf(w, bfhi(v[2]), acc[5]);
            acc[6] = fmaf(w, bflo(v[3]), acc[6]);
            acc[7] = fmaf(w, bfhi(v[3]), acc[7]);
        }
    }
    if (half == 0){
        float4 p0 = {acc[0],acc[1],acc[2],acc[3]};
        float4 p1 = {acc[4],acc[5],acc[6],acc[7]};
        *(float4*)&Cpart[cr_][cc0]   = p0;
        *(float4*)&Cpart[cr_][cc0+4] = p1;
    }
    __syncthreads();

    // ---- P3b: combine halves -> Cb bf16 ----
    if (half == 1){
        float4 p0 = *(const float4*)&Cpart[cr_][cc0];
        float4 p1 = *(const float4*)&Cpart[cr_][cc0+4];
        uint4 ov;
        ov.x = pack2(acc[0]+p0.x, acc[1]+p0.y);
        ov.y = pack2(acc[2]+p0.z, acc[3]+p0.w);
        ov.z = pack2(acc[4]+p1.x, acc[5]+p1.y);
        ov.w = pack2(acc[6]+p1.z, acc[7]+p1.w);
        *(uint4*)&Cb[cr_][cc0] = ov;
    }
    __syncthreads();

    // ---- P4: g = tanh([e|ctx]@Bcmb + combB), 1 tile per wave ----
    {
        const bf16_t* ae = &Eb[lane&15][(lane>>4)*8];
        const bf16_t* ac = &Cb[lane&15][(lane>>4)*8];
        f32x4 c = {0,0,0,0};
        #pragma unroll
        for (int kt=0; kt<16; kt++){
            bf16x8 a = (kt<8)? *(const bf16x8*)(ae + kt*32)
                             : *(const bf16x8*)(ac + (kt-8)*32);
            bf16x8 b = *(const bf16x8*)((const char*)Bcmb + (size_t)(((wave<<4)+kt)<<10) + loff);
            c = MFMA(a, b, c, 0,0,0);
        }
        int n = (wave<<4) + (lane&15);
        float bbn = combB[n];
        #pragma unroll
        for (int q=0;q<4;q++){
            int r = ((lane>>4)<<2) + q;
            g_out[(size_t)(b0+r)*HD + n] = f2bf(tanhf(c[q] + bbn));
        }
    }
}

// ---------------------------------------------------------------------------
// ys[79] = h_final(f32) @ outW^T + outB. grid 64x256.
// ---------------------------------------------------------------------------
__global__ __launch_bounds__(256) void final79(
    const float* __restrict__ hf, const float* __restrict__ outW,
    const float* __restrict__ outB, float* __restrict__ ys)
{
    __shared__ float hs[16][260];
    __shared__ float ow[16*260];
    int tid = threadIdx.x, b0 = blockIdx.x*16;
    for (int i=tid;i<4096;i+=256){ int o2=i>>8,k=i&255; ow[o2*260+k]=outW[(size_t)o2*HD+k]; }
    for (int i=tid;i<4096;i+=256){ int r=i>>8,k=i&255; hs[r][k]=hf[(size_t)(b0+r)*HD+k]; }
    __syncthreads();
    int r=tid>>4, o=tid&15;
    float acc=outB[o];
    const float* w=&ow[o*260];
    for(int k=0;k<256;k++) acc += hs[r][k]*w[k];
    ys[((size_t)79*BATCH + b0+r)*KOUT + o] = acc;
}

// ---------------------------------------------------------------------------
extern "C" void kernel_launch(void* const* d_in, const int* in_sizes, int n_in,
                              void* d_out, int out_size, void* d_ws, size_t ws_size,
                              hipStream_t stream) {
    const float* pre_x    = (const float*)d_in[0];
    const float* pre_y    = (const float*)d_in[1];
    const float* fwd_x    = (const float*)d_in[2];
    const float* enc_embW = (const float*)d_in[3];
    const float* enc_embB = (const float*)d_in[4];
    const float* enc_Wih  = (const float*)d_in[5];
    const float* enc_Whh  = (const float*)d_in[6];
    const float* enc_bih  = (const float*)d_in[7];
    const float* enc_bhh  = (const float*)d_in[8];
    const float* dec_embW = (const float*)d_in[9];
    const float* dec_embB = (const float*)d_in[10];
    const float* attn_W   = (const float*)d_in[11];
    const float* attn_b   = (const float*)d_in[12];
    const float* comb_W   = (const float*)d_in[13];
    const float* comb_b   = (const float*)d_in[14];
    const float* dec_Wih  = (const float*)d_in[15];
    const float* dec_Whh  = (const float*)d_in[16];
    const float* dec_bih  = (const float*)d_in[17];
    const float* dec_bhh  = (const float*)d_in[18];
    const float* out_W    = (const float*)d_in[19];
    const float* out_b    = (const float*)d_in[20];
    float* out = (float*)d_out;

    char* ws = (char*)d_ws;
    size_t o = 0;
    auto alloc = [&](size_t bytes)->char*{
        char* p = ws + o; o = (o + bytes + 255) & ~(size_t)255; return p;
    };
    bf16_t* EMB     = (bf16_t*)alloc((size_t)LPRE*BATCH*HD*2);     // 31.5 MB
    bf16_t* ENC_OUT = (bf16_t*)alloc((size_t)LPRE*BATCH*HD*2);     // 31.5 MB [t][B][H]
    bf16_t* FXB     = (bf16_t*)alloc((size_t)LFWD*BATCH*KIN*2);
    float*  HF0     = (float*) alloc((size_t)BATCH*HD*4);
    float*  HF1     = (float*) alloc((size_t)BATCH*HD*4);
    bf16_t* HB0     = (bf16_t*)alloc((size_t)BATCH*HD*2);
    bf16_t* HB1     = (bf16_t*)alloc((size_t)BATCH*HD*2);
    bf16_t* GBUF    = (bf16_t*)alloc((size_t)BATCH*HD*2);
    bf16_t* DUMMY   = (bf16_t*)alloc((size_t)BATCH*HD*2);
    float*  WFUSE   = (float*) alloc((size_t)256*256*4);
    float*  EBIAS   = (float*) alloc(256*4);
    float*  LB      = (float*) alloc(80*4);
    float*  LB0     = (float*) alloc(80*4);
    bf16_t* PACK_ENC = (bf16_t*)alloc(786432);
    bf16_t* PACK_DEC = (bf16_t*)alloc(786432);
    bf16_t* PACK_CMB = (bf16_t*)alloc(262144);
    bf16_t* PACK_E   = (bf16_t*)alloc(147456);
    bf16_t* PACK_BL  = (bf16_t*)alloc(46080);
    bf16_t* PACK_BL0 = (bf16_t*)alloc(46080);
    bf16_t* PACK_OUT = (bf16_t*)alloc(8192);

    hipMemsetAsync(HF0, 0, (size_t)BATCH*HD*4, stream);
    hipMemsetAsync(HB0, 0, (size_t)BATCH*HD*2, stream);

    dim3 blk(256);
    // ---- prep (one-time) ----
    emb_kernel<<<dim3(64,60), blk, 0, stream>>>(pre_x, pre_y, enc_embW, enc_embB, EMB);
    fxconv<<<dim3(1280), blk, 0, stream>>>(fwd_x, FXB);
    pack_gru<<<dim3(192), blk, 0, stream>>>(enc_Wih, enc_Whh, PACK_ENC);
    pack_gru<<<dim3(192), blk, 0, stream>>>(dec_Wih, dec_Whh, PACK_DEC);
    pack_B512<<<dim3(64), blk, 0, stream>>>(comb_W, PACK_CMB);
    wfuse_kernel<<<dim3(257), blk, 0, stream>>>(dec_embW, dec_embB, out_W, out_b, WFUSE, EBIAS);
    pack_e<<<dim3(36), blk, 0, stream>>>(WFUSE, dec_embW, PACK_E);
    pack_logits<<<dim3(24), blk, 0, stream>>>(WFUSE, dec_embW, attn_W, attn_b, dec_embB,
                                              EBIAS, PACK_BL, PACK_BL0, LB, LB0);
    pack_out<<<dim3(2), blk, 0, stream>>>(out_W, PACK_OUT);

    float*  HF[2] = {HF0, HF1};
    bf16_t* HB[2] = {HB0, HB1};
    int p = 0;

    // ---- encoder: 60 proven gru_step dispatches ----
    for (int t = 0; t < LPRE; t++){
        gru_step<<<dim3(64,4), blk, 0, stream>>>(
            EMB + (size_t)t*BATCH*HD, HB[p], PACK_ENC, enc_bih, enc_bhh,
            HF[p], HF[p^1], HB[p^1], ENC_OUT + (size_t)t*BATCH*HD);
        p ^= 1;
    }
    // ---- decoder: 2 dispatches per step ----
    for (int t = 0; t < LFWD; t++){
        const bf16_t* fxt = FXB + (size_t)t*BATCH*KIN;
        dec_front<<<dim3(64), dim3(1024), 0, stream>>>(
            HB[p], fxt, ENC_OUT,
            PACK_E, t ? PACK_BL : PACK_BL0, PACK_CMB, PACK_OUT,
            t ? EBIAS : dec_embB, t ? LB : LB0, comb_b, out_b,
            t, GBUF, out);
        gru_step<<<dim3(64,4), blk, 0, stream>>>(
            GBUF, HB[p], PACK_DEC, dec_bih, dec_bhh,
            HF[p], HF[p^1], HB[p^1], DUMMY);
        p ^= 1;
    }
    final79<<<dim3(64), blk, 0, stream>>>(HF[p], out_W, out_b, out);
}

// Round 6
// 2462.412 us; speedup vs baseline: 2.4254x; 1.0073x over previous
//
#include <hip/hip_runtime.h>
#include <hip/hip_bf16.h>

#define BATCH 1024
#define HD 256
#define MLEN 80
#define LPRE 60
#define LFWD 80
#define KIN 32
#define KOUT 16

typedef unsigned short bf16_t;
typedef __attribute__((ext_vector_type(8))) short bf16x8;
typedef __attribute__((ext_vector_type(4))) float f32x4;
typedef __attribute__((ext_vector_type(4))) unsigned u32x4;

#define MFMA __builtin_amdgcn_mfma_f32_16x16x32_bf16

__device__ __forceinline__ float bf2f(bf16_t v){ return __uint_as_float(((unsigned)v)<<16); }
__device__ __forceinline__ bf16_t f2bf(float f){
    unsigned u = __float_as_uint(f);
    return (bf16_t)((u + 0x7FFFu + ((u>>16)&1u)) >> 16);
}
__device__ __forceinline__ unsigned pack2(float lo, float hi){
    return (unsigned)f2bf(lo) | ((unsigned)f2bf(hi)<<16);
}
__device__ __forceinline__ float bflo(unsigned d){ return __uint_as_float(d<<16); }
__device__ __forceinline__ float bfhi(unsigned d){ return __uint_as_float(d & 0xffff0000u); }
__device__ __forceinline__ float sigm(float x){ return 1.0f/(1.0f+__expf(-x)); }

// Packed-B byte offsets inside a GRU weight pack (4 N-groups):
// r:[0,262144) z:[262144,524288) in:[524288,655360) hn:[655360,786432)
#define OFF_Z  262144
#define OFF_IN 524288
#define OFF_HN 655360

// ---------------------------------------------------------------------------
// Pack GRU weights: B[k][n] fragment-tiled bf16. grid 192x256 (one 16B chunk/thread)
// ---------------------------------------------------------------------------
__global__ void pack_gru(const float* __restrict__ Wih, const float* __restrict__ Whh,
                         bf16_t* __restrict__ dst)
{
    int T = blockIdx.x*256 + threadIdx.x;   // < 49152
    int grp, local;
    if (T < 16384){ grp=0; local=T; }
    else if (T < 32768){ grp=1; local=T-16384; }
    else if (T < 40960){ grp=2; local=T-32768; }
    else { grp=3; local=T-40960; }
    int nkt = (grp<2)?16:8;
    int nt  = local / (nkt*64);
    int rem = local - nt*(nkt*64);
    int kt  = rem >> 6;
    int l   = rem & 63;
    int n   = nt*16 + (l&15);
    int k0  = kt*32 + ((l>>4)<<3);
    unsigned w[4];
    #pragma unroll
    for (int h2=0; h2<4; h2++){
        float v[2];
        #pragma unroll
        for (int s=0; s<2; s++){
            int k = k0 + h2*2 + s;
            if (grp==0)      v[s] = (k<256)? Wih[(size_t)n*HD + k]       : Whh[(size_t)n*HD + (k-256)];
            else if (grp==1) v[s] = (k<256)? Wih[(size_t)(256+n)*HD + k] : Whh[(size_t)(256+n)*HD + (k-256)];
            else if (grp==2) v[s] = Wih[(size_t)(512+n)*HD + k];
            else             v[s] = Whh[(size_t)(512+n)*HD + k];
        }
        w[h2] = pack2(v[0], v[1]);
    }
    uint4 u = {w[0],w[1],w[2],w[3]};
    *(uint4*)((char*)dst + (size_t)T*16) = u;
}

// ---------------------------------------------------------------------------
// Pack K=512,N=256 B from W[256][512] (combW): B[k][n]=W[n][k]. grid 64x256
// ---------------------------------------------------------------------------
__global__ void pack_B512(const float* __restrict__ W, bf16_t* __restrict__ dst)
{
    int T = blockIdx.x*256 + threadIdx.x;   // < 16384
    int nt = T >> 10, kt = (T>>6)&15, l = T&63;
    int n = nt*16 + (l&15);
    int k0 = kt*32 + ((l>>4)<<3);
    unsigned w[4];
    #pragma unroll
    for (int h2=0; h2<4; h2++)
        w[h2] = pack2(W[(size_t)n*512 + k0+h2*2], W[(size_t)n*512 + k0+h2*2+1]);
    uint4 u = {w[0],w[1],w[2],w[3]};
    *(uint4*)((char*)dst + (size_t)T*16) = u;
}

// ---------------------------------------------------------------------------
// Wfuse[k][n] = sum_o dembW[n][o]*outW[o][k]; e_bias[n]=dembB[n]+sum_o outB[o]*dembW[n][o]
// grid 257x256
// ---------------------------------------------------------------------------
__global__ void wfuse_kernel(const float* __restrict__ dembW, const float* __restrict__ dembB,
                             const float* __restrict__ outW, const float* __restrict__ outB,
                             float* __restrict__ Wfuse, float* __restrict__ ebias)
{
    int T = blockIdx.x*256 + threadIdx.x;
    if (T < 65536){
        int k = T >> 8, n = T & 255;
        float acc = 0.f;
        #pragma unroll
        for (int o=0;o<16;o++) acc += dembW[(size_t)n*48 + o]*outW[(size_t)o*HD + k];
        Wfuse[(size_t)k*HD + n] = acc;
    } else if (T < 65792){
        int n = T - 65536;
        float acc = dembB[n];
        #pragma unroll
        for (int o=0;o<16;o++) acc += outB[o]*dembW[(size_t)n*48 + o];
        ebias[n] = acc;
    }
}

// ---------------------------------------------------------------------------
// Pack B_e [K=288][N=256]: kt<8 -> Wfuse[k][n]; kt==8 -> dembW[n][16+k']. grid 36x256
// ---------------------------------------------------------------------------
__global__ void pack_e(const float* __restrict__ Wfuse, const float* __restrict__ dembW,
                       bf16_t* __restrict__ dst)
{
    int T = blockIdx.x*256 + threadIdx.x;   // < 9216
    int nt = T/576, rem = T - nt*576;
    int kt = rem >> 6, l = rem & 63;
    int n = nt*16 + (l&15);
    int k0 = kt*32 + ((l>>4)<<3);
    unsigned w[4];
    #pragma unroll
    for (int h2=0; h2<4; h2++){
        float v[2];
        #pragma unroll
        for (int s=0;s<2;s++){
            int k = k0 + h2*2 + s;
            v[s] = (kt<8)? Wfuse[(size_t)k*HD + n] : dembW[(size_t)n*48 + 16 + (k-256)];
        }
        w[h2] = pack2(v[0], v[1]);
    }
    uint4 u = {w[0],w[1],w[2],w[3]};
    *(uint4*)((char*)dst + (size_t)T*16) = u;
}

// ---------------------------------------------------------------------------
// Pack logits B (t>=1 and t==0 variants) + bias vectors. grid 24x256
// ---------------------------------------------------------------------------
__global__ void pack_logits(const float* __restrict__ Wfuse, const float* __restrict__ dembW,
                            const float* __restrict__ attW, const float* __restrict__ attB,
                            const float* __restrict__ dembB, const float* __restrict__ ebias,
                            bf16_t* __restrict__ BL, bf16_t* __restrict__ BL0,
                            float* __restrict__ lb, float* __restrict__ lb0)
{
    int T = blockIdx.x*256 + threadIdx.x;
    if (T < 5760){
        int variant = (T < 2880) ? 0 : 1;
        int local = variant ? (T-2880) : T;
        int nt = local/576, rem = local - nt*576;
        int kt = rem >> 6, l = rem & 63;
        int m  = nt*16 + (l&15);
        int k0 = kt*32 + ((l>>4)<<3);
        unsigned w[4];
        #pragma unroll
        for (int h2=0; h2<4; h2++){
            float v[2];
            for (int s=0;s<2;s++){
                int k = k0 + h2*2 + s;
                float acc;
                if (kt < 8){
                    if (variant == 0){
                        acc = attW[(size_t)m*512 + 256 + k];
                        for (int n=0;n<256;n++) acc += Wfuse[(size_t)k*HD + n]*attW[(size_t)m*512 + n];
                    } else {
                        acc = attW[(size_t)m*512 + 256 + k];
                    }
                } else {
                    int kp = k - 256;
                    acc = 0.f;
                    for (int n=0;n<256;n++) acc += dembW[(size_t)n*48 + 16 + kp]*attW[(size_t)m*512 + n];
                }
                v[s] = acc;
            }
            w[h2] = pack2(v[0], v[1]);
        }
        uint4 u = {w[0],w[1],w[2],w[3]};
        bf16_t* d = variant ? BL0 : BL;
        *(uint4*)((char*)d + (size_t)local*16) = u;
    } else if (T < 5840){
        int m = T - 5760;
        float acc = attB[m];
        for (int n=0;n<256;n++) acc += ebias[n]*attW[(size_t)m*512 + n];
        lb[m] = acc;
    } else if (T < 5920){
        int m = T - 5840;
        float acc = attB[m];
        for (int n=0;n<256;n++) acc += dembB[n]*attW[(size_t)m*512 + n];
        lb0[m] = acc;
    }
}

// ---------------------------------------------------------------------------
// Pack B_out [K=256][N=16] from outW[16][256]. grid 2x256 (512 chunks)
// ---------------------------------------------------------------------------
__global__ void pack_out(const float* __restrict__ outW, bf16_t* __restrict__ dst)
{
    int T = blockIdx.x*256 + threadIdx.x;   // < 512
    int kt = T >> 6, l = T & 63;
    int n  = l & 15;
    int k0 = kt*32 + ((l>>4)<<3);
    unsigned w[4];
    #pragma unroll
    for (int h2=0; h2<4; h2++)
        w[h2] = pack2(outW[(size_t)n*HD + k0+h2*2], outW[(size_t)n*HD + k0+h2*2+1]);
    uint4 u = {w[0],w[1],w[2],w[3]};
    *(uint4*)((char*)dst + (size_t)T*16) = u;
}

// ---------------------------------------------------------------------------
// All 60 encoder embeddings -> bf16. grid (64,60)x256
// ---------------------------------------------------------------------------
__global__ __launch_bounds__(256) void emb_kernel(
    const float* __restrict__ px, const float* __restrict__ py,
    const float* __restrict__ embW, const float* __restrict__ embB,
    bf16_t* __restrict__ emb)
{
    __shared__ float Ws[256*49];
    __shared__ float xy[16][48];
    __shared__ float bs[256];
    int t = blockIdx.y, b0 = blockIdx.x*16, tid = threadIdx.x;
    for (int i = tid; i < 256*48; i += 256){ int n=i/48, k=i-n*48; Ws[n*49+k]=embW[i]; }
    bs[tid] = embB[tid];
    for (int i = tid; i < 16*48; i += 256){
        int r=i/48, k=i-r*48;
        xy[r][k] = (k<KIN)? px[((size_t)t*BATCH + b0+r)*KIN + k]
                          : py[((size_t)t*BATCH + b0+r)*KOUT + (k-KIN)];
    }
    __syncthreads();
    int n = tid;
    const float* w = &Ws[n*49];
    for (int r=0;r<16;r++){
        float acc = bs[n];
        #pragma unroll
        for (int k=0;k<48;k++) acc += xy[r][k]*w[k];
        emb[((size_t)t*BATCH + b0+r)*HD + n] = f2bf(acc);
    }
}

// fx f32 -> bf16. grid 1280x256, one 8-elem chunk/thread
__global__ void fxconv(const float* __restrict__ fx, bf16_t* __restrict__ dst)
{
    size_t i = (size_t)blockIdx.x*256 + threadIdx.x;
    const float4* s = (const float4*)(fx + i*8);
    float4 a = s[0], b = s[1];
    uint4 u = { pack2(a.x,a.y), pack2(a.z,a.w), pack2(b.x,b.y), pack2(b.z,b.w) };
    *(uint4*)(dst + i*8) = u;
}

// ---------------------------------------------------------------------------
// gru_step2: K-split GRU step. grid (64,4) x 512 threads (8 waves).
// Wave-pair per j-tile: half 0 = kt 0..7 (full ci + half cr/cz),
// half 1 = kt 8..15 (full ch + half cr/cz). Partials combined via LDS;
// epilogue by half-1 waves. 2 waves/SIMD (vs 1 in the 256-thr version),
// per-wave serial load chain halved (96 -> 48 B-loads).
// ---------------------------------------------------------------------------
__global__ __launch_bounds__(512) void gru_step2(
    const bf16_t* __restrict__ A0, const bf16_t* __restrict__ A1,
    const bf16_t* __restrict__ Bp,
    const float* __restrict__ bih, const float* __restrict__ bhh,
    const float* __restrict__ hprev, float* __restrict__ hnext,
    bf16_t* __restrict__ hnext_bf, bf16_t* __restrict__ extra_bf)
{
    __shared__ __align__(16) bf16_t As[16][520];
    __shared__ __align__(16) f32x4 redR[4][64];
    __shared__ __align__(16) f32x4 redZ[4][64];
    __shared__ __align__(16) f32x4 redI[4][64];
    int tid = threadIdx.x, b0 = blockIdx.x*16;
    for (int i = tid; i < 1024; i += 512){
        int r = i>>6, c = i&63;
        const bf16_t* src = (c<32)? (A0 + (size_t)(b0+r)*HD + c*8)
                                  : (A1 + (size_t)(b0+r)*HD + (c-32)*8);
        *(uint4*)&As[r][c*8] = *(const uint4*)src;
    }
    __syncthreads();
    int lane = tid & 63, wave = tid >> 6;        // 8 waves
    int pairId = wave >> 1, half = wave & 1;
    int jt = blockIdx.y*4 + pairId;
    const char* arow = (const char*)&As[lane&15][(lane>>4)*8];
    const char* bpc = (const char*)Bp;
    size_t loff = (size_t)lane*16;
    size_t offX = half ? (size_t)OFF_HN : (size_t)OFF_IN;
    int kt0 = half*8;
    f32x4 cr={0,0,0,0}, cz={0,0,0,0}, cx={0,0,0,0};   // cx = ci (half0) / ch (half1)
    #pragma unroll
    for (int k8=0; k8<8; k8++){
        int kt = kt0 + k8;
        bf16x8 a  = *(const bf16x8*)(arow + kt*64);
        bf16x8 br = *(const bf16x8*)(bpc + (size_t)(((jt<<4)+kt)<<10) + loff);
        bf16x8 bz = *(const bf16x8*)(bpc + OFF_Z + (size_t)(((jt<<4)+kt)<<10) + loff);
        bf16x8 bx = *(const bf16x8*)(bpc + offX + (size_t)(((jt<<3)+k8)<<10) + loff);
        cr = MFMA(a, br, cr, 0,0,0);
        cz = MFMA(a, bz, cz, 0,0,0);
        cx = MFMA(a, bx, cx, 0,0,0);
    }
    if (half == 0){
        redR[pairId][lane] = cr;
        redZ[pairId][lane] = cz;
        redI[pairId][lane] = cx;
    }
    __syncthreads();
    if (half == 1){
        f32x4 crA = redR[pairId][lane];
        f32x4 czA = redZ[pairId][lane];
        f32x4 ci  = redI[pairId][lane];
        int j = (jt<<4) + (lane&15);
        float b_r = bih[j] + bhh[j];
        float b_z = bih[256+j] + bhh[256+j];
        float b_i = bih[512+j], b_h = bhh[512+j];
        #pragma unroll
        for (int q=0;q<4;q++){
            int b = b0 + ((lane>>4)<<2) + q;
            float rv = sigm(cr[q] + crA[q] + b_r);
            float zv = sigm(cz[q] + czA[q] + b_z);
            float nv = tanhf(ci[q] + b_i + rv*(cx[q] + b_h));
            float h2 = (1.0f - zv)*nv + zv*hprev[(size_t)b*HD + j];
            hnext[(size_t)b*HD + j] = h2;
            bf16_t hb = f2bf(h2);
            hnext_bf[(size_t)b*HD + j] = hb;
            extra_bf[(size_t)b*HD + j] = hb;
        }
    }
}

// ---------------------------------------------------------------------------
// dec_front v5: 1024 threads (16 waves). One dispatch fusing
// e + logits + ys_{t-1} + softmax + ctx + comb. (verified round 5)
// ---------------------------------------------------------------------------
__global__ __launch_bounds__(1024) void dec_front(
    const bf16_t* __restrict__ hbf, const bf16_t* __restrict__ fxt,
    const bf16_t* __restrict__ enc_out,
    const bf16_t* __restrict__ Be, const bf16_t* __restrict__ BL,
    const bf16_t* __restrict__ Bcmb, const bf16_t* __restrict__ Bout,
    const float* __restrict__ ebp, const float* __restrict__ lbp,
    const float* __restrict__ combB, const float* __restrict__ outB,
    int t, bf16_t* __restrict__ g_out, float* __restrict__ out)
{
    __shared__ __align__(16) bf16_t As[16][296];   // [h(256) | fx(32)]
    __shared__ __align__(16) bf16_t Eb[16][264];   // e
    __shared__ __align__(16) bf16_t Cb[16][264];   // ctx
    __shared__ float awL[16][84];                  // logits -> aw
    __shared__ float Cpart[16][256];               // ctx partial (m 0..29)

    int tid = threadIdx.x, b0 = blockIdx.x*16;

    // ---- stage As ----
    if (tid < 576){
        int r = tid/36, c = tid - r*36;
        const bf16_t* src = (c<32)? (hbf + (size_t)(b0+r)*HD + c*8)
                                  : (fxt + (size_t)(b0+r)*KIN + (c-32)*8);
        *(uint4*)&As[r][c*8] = *(const uint4*)src;
    }

    // ---- ctx geometry + issue-early prefetch (independent of As/aw) ----
    int half = tid >> 9;              // 0: m 0..29, 1: m 30..59
    int u    = tid & 511;
    int cr_  = u >> 5;                // row 0..15
    int cc0  = (u & 31) * 8;          // col chunk
    const bf16_t* cbp = enc_out + ((size_t)(half*30)*BATCH + (b0+cr_))*HD + cc0;
    u32x4 pf[10];
    #pragma unroll
    for (int i=0;i<10;i++) pf[i] = *(const u32x4*)(cbp + (size_t)i*BATCH*HD);

    __syncthreads();

    int lane = tid & 63, wave = tid >> 6;     // wave 0..15
    const bf16_t* arow = &As[lane&15][(lane>>4)*8];
    size_t loff = (size_t)lane*16;
    int ke0 = t ? 0 : 8;

    // ---- P1: 22 MFMA tiles over 16 waves (1-2 tiles/wave) ----
    {   // e-tile n = wave
        f32x4 c = {0,0,0,0};
        for (int kt = ke0; kt < 9; kt++){
            bf16x8 a = *(const bf16x8*)(arow + kt*32);
            bf16x8 b = *(const bf16x8*)((const char*)Be + (size_t)((wave*9+kt)<<10) + loff);
            c = MFMA(a, b, c, 0,0,0);
        }
        int n = (wave<<4) + (lane&15);
        float bbn = ebp[n];
        #pragma unroll
        for (int q=0;q<4;q++) Eb[((lane>>4)<<2)+q][n] = f2bf(c[q] + bbn);
    }
    if (wave < 5){
        // logits tile nt = wave
        f32x4 c = {0,0,0,0};
        #pragma unroll
        for (int kt = 0; kt < 9; kt++){
            bf16x8 a = *(const bf16x8*)(arow + kt*32);
            bf16x8 b = *(const bf16x8*)((const char*)BL + (size_t)((wave*9+kt)<<10) + loff);
            c = MFMA(a, b, c, 0,0,0);
        }
        int m = (wave<<4) + (lane&15);
        float bbm = lbp[m];
        #pragma unroll
        for (int q=0;q<4;q++) awL[((lane>>4)<<2)+q][m] = c[q] + bbm;
    } else if (wave == 5 && t > 0){
        // ys[t-1] = h @ outW^T + outB
        f32x4 c = {0,0,0,0};
        #pragma unroll
        for (int kt = 0; kt < 8; kt++){
            bf16x8 a = *(const bf16x8*)(arow + kt*32);
            bf16x8 b = *(const bf16x8*)((const char*)Bout + (size_t)(kt<<10) + loff);
            c = MFMA(a, b, c, 0,0,0);
        }
        int o = lane & 15;
        float bo = outB[o];
        #pragma unroll
        for (int q=0;q<4;q++){
            int r = ((lane>>4)<<2) + q;
            out[((size_t)(t-1)*BATCH + b0+r)*KOUT + o] = c[q] + bo;
        }
    }
    __syncthreads();

    // ---- P2: softmax over awL rows (16 threads/row, shuffle reduce) ----
    if (tid < 256){
        int r2 = tid >> 4, l2 = tid & 15;
        float vmax = -1e30f;
        for (int m=l2; m<80; m+=16) vmax = fmaxf(vmax, awL[r2][m]);
        #pragma unroll
        for (int k=1; k<16; k<<=1) vmax = fmaxf(vmax, __shfl_xor(vmax, k, 16));
        float ps = 0.f;
        for (int m=l2; m<80; m+=16){ float v = __expf(awL[r2][m]-vmax); awL[r2][m]=v; ps += v; }
        #pragma unroll
        for (int k=1; k<16; k<<=1) ps += __shfl_xor(ps, k, 16);
        float inv = 1.0f/ps;
        for (int m=l2; m<80; m+=16) awL[r2][m] *= inv;
    }
    __syncthreads();

    // ---- P3a: partial ctx, each thread 30 m (10 prefetched) ----
    float acc[8];
    #pragma unroll
    for (int i=0;i<8;i++) acc[i] = 0.f;
    {
        const float* awr = &awL[cr_][half*30];
        #pragma unroll
        for (int i=0;i<10;i++){
            float w = awr[i];
            acc[0] = fmaf(w, bflo(pf[i][0]), acc[0]);
            acc[1] = fmaf(w, bfhi(pf[i][0]), acc[1]);
            acc[2] = fmaf(w, bflo(pf[i][1]), acc[2]);
            acc[3] = fmaf(w, bfhi(pf[i][1]), acc[3]);
            acc[4] = fmaf(w, bflo(pf[i][2]), acc[4]);
            acc[5] = fmaf(w, bfhi(pf[i][2]), acc[5]);
            acc[6] = fmaf(w, bflo(pf[i][3]), acc[6]);
            acc[7] = fmaf(w, bfhi(pf[i][3]), acc[7]);
        }
        #pragma unroll 5
        for (int i=10;i<30;i++){
            u32x4 v = *(const u32x4*)(cbp + (size_t)i*BATCH*HD);
            float w = awr[i];
            acc[0] = fmaf(w, bflo(v[0]), acc[0]);
            acc[1] = fmaf(w, bfhi(v[0]), acc[1]);
            acc[2] = fmaf(w, bflo(v[1]), acc[2]);
            acc[3] = fmaf(w, bfhi(v[1]), acc[3]);
            acc[4] = fmaf(w, bflo(v[2]), acc[4]);
            acc[5] = fmaf(w, bfhi(v[2]), acc[5]);
            acc[6] = fmaf(w, bflo(v[3]), acc[6]);
            acc[7] = fmaf(w, bfhi(v[3]), acc[7]);
        }
    }
    if (half == 0){
        float4 p0 = {acc[0],acc[1],acc[2],acc[3]};
        float4 p1 = {acc[4],acc[5],acc[6],acc[7]};
        *(float4*)&Cpart[cr_][cc0]   = p0;
        *(float4*)&Cpart[cr_][cc0+4] = p1;
    }
    __syncthreads();

    // ---- P3b: combine halves -> Cb bf16 ----
    if (half == 1){
        float4 p0 = *(const float4*)&Cpart[cr_][cc0];
        float4 p1 = *(const float4*)&Cpart[cr_][cc0+4];
        uint4 ov;
        ov.x = pack2(acc[0]+p0.x, acc[1]+p0.y);
        ov.y = pack2(acc[2]+p0.z, acc[3]+p0.w);
        ov.z = pack2(acc[4]+p1.x, acc[5]+p1.y);
        ov.w = pack2(acc[6]+p1.z, acc[7]+p1.w);
        *(uint4*)&Cb[cr_][cc0] = ov;
    }
    __syncthreads();

    // ---- P4: g = tanh([e|ctx]@Bcmb + combB), 1 tile per wave ----
    {
        const bf16_t* ae = &Eb[lane&15][(lane>>4)*8];
        const bf16_t* ac = &Cb[lane&15][(lane>>4)*8];
        f32x4 c = {0,0,0,0};
        #pragma unroll
        for (int kt=0; kt<16; kt++){
            bf16x8 a = (kt<8)? *(const bf16x8*)(ae + kt*32)
                             : *(const bf16x8*)(ac + (kt-8)*32);
            bf16x8 b = *(const bf16x8*)((const char*)Bcmb + (size_t)(((wave<<4)+kt)<<10) + loff);
            c = MFMA(a, b, c, 0,0,0);
        }
        int n = (wave<<4) + (lane&15);
        float bbn = combB[n];
        #pragma unroll
        for (int q=0;q<4;q++){
            int r = ((lane>>4)<<2) + q;
            g_out[(size_t)(b0+r)*HD + n] = f2bf(tanhf(c[q] + bbn));
        }
    }
}

// ---------------------------------------------------------------------------
// ys[79] = h_final(f32) @ outW^T + outB. grid 64x256.
// ---------------------------------------------------------------------------
__global__ __launch_bounds__(256) void final79(
    const float* __restrict__ hf, const float* __restrict__ outW,
    const float* __restrict__ outB, float* __restrict__ ys)
{
    __shared__ float hs[16][260];
    __shared__ float ow[16*260];
    int tid = threadIdx.x, b0 = blockIdx.x*16;
    for (int i=tid;i<4096;i+=256){ int o2=i>>8,k=i&255; ow[o2*260+k]=outW[(size_t)o2*HD+k]; }
    for (int i=tid;i<4096;i+=256){ int r=i>>8,k=i&255; hs[r][k]=hf[(size_t)(b0+r)*HD+k]; }
    __syncthreads();
    int r=tid>>4, o=tid&15;
    float acc=outB[o];
    const float* w=&ow[o*260];
    for(int k=0;k<256;k++) acc += hs[r][k]*w[k];
    ys[((size_t)79*BATCH + b0+r)*KOUT + o] = acc;
}

// ---------------------------------------------------------------------------
extern "C" void kernel_launch(void* const* d_in, const int* in_sizes, int n_in,
                              void* d_out, int out_size, void* d_ws, size_t ws_size,
                              hipStream_t stream) {
    const float* pre_x    = (const float*)d_in[0];
    const float* pre_y    = (const float*)d_in[1];
    const float* fwd_x    = (const float*)d_in[2];
    const float* enc_embW = (const float*)d_in[3];
    const float* enc_embB = (const float*)d_in[4];
    const float* enc_Wih  = (const float*)d_in[5];
    const float* enc_Whh  = (const float*)d_in[6];
    const float* enc_bih  = (const float*)d_in[7];
    const float* enc_bhh  = (const float*)d_in[8];
    const float* dec_embW = (const float*)d_in[9];
    const float* dec_embB = (const float*)d_in[10];
    const float* attn_W   = (const float*)d_in[11];
    const float* attn_b   = (const float*)d_in[12];
    const float* comb_W   = (const float*)d_in[13];
    const float* comb_b   = (const float*)d_in[14];
    const float* dec_Wih  = (const float*)d_in[15];
    const float* dec_Whh  = (const float*)d_in[16];
    const float* dec_bih  = (const float*)d_in[17];
    const float* dec_bhh  = (const float*)d_in[18];
    const float* out_W    = (const float*)d_in[19];
    const float* out_b    = (const float*)d_in[20];
    float* out = (float*)d_out;

    char* ws = (char*)d_ws;
    size_t o = 0;
    auto alloc = [&](size_t bytes)->char*{
        char* p = ws + o; o = (o + bytes + 255) & ~(size_t)255; return p;
    };
    bf16_t* EMB     = (bf16_t*)alloc((size_t)LPRE*BATCH*HD*2);     // 31.5 MB
    bf16_t* ENC_OUT = (bf16_t*)alloc((size_t)LPRE*BATCH*HD*2);     // 31.5 MB [t][B][H]
    bf16_t* FXB     = (bf16_t*)alloc((size_t)LFWD*BATCH*KIN*2);
    float*  HF0     = (float*) alloc((size_t)BATCH*HD*4);
    float*  HF1     = (float*) alloc((size_t)BATCH*HD*4);
    bf16_t* HB0     = (bf16_t*)alloc((size_t)BATCH*HD*2);
    bf16_t* HB1     = (bf16_t*)alloc((size_t)BATCH*HD*2);
    bf16_t* GBUF    = (bf16_t*)alloc((size_t)BATCH*HD*2);
    bf16_t* DUMMY   = (bf16_t*)alloc((size_t)BATCH*HD*2);
    float*  WFUSE   = (float*) alloc((size_t)256*256*4);
    float*  EBIAS   = (float*) alloc(256*4);
    float*  LB      = (float*) alloc(80*4);
    float*  LB0     = (float*) alloc(80*4);
    bf16_t* PACK_ENC = (bf16_t*)alloc(786432);
    bf16_t* PACK_DEC = (bf16_t*)alloc(786432);
    bf16_t* PACK_CMB = (bf16_t*)alloc(262144);
    bf16_t* PACK_E   = (bf16_t*)alloc(147456);
    bf16_t* PACK_BL  = (bf16_t*)alloc(46080);
    bf16_t* PACK_BL0 = (bf16_t*)alloc(46080);
    bf16_t* PACK_OUT = (bf16_t*)alloc(8192);

    hipMemsetAsync(HF0, 0, (size_t)BATCH*HD*4, stream);
    hipMemsetAsync(HB0, 0, (size_t)BATCH*HD*2, stream);

    dim3 blk(256);
    // ---- prep (one-time) ----
    emb_kernel<<<dim3(64,60), blk, 0, stream>>>(pre_x, pre_y, enc_embW, enc_embB, EMB);
    fxconv<<<dim3(1280), blk, 0, stream>>>(fwd_x, FXB);
    pack_gru<<<dim3(192), blk, 0, stream>>>(enc_Wih, enc_Whh, PACK_ENC);
    pack_gru<<<dim3(192), blk, 0, stream>>>(dec_Wih, dec_Whh, PACK_DEC);
    pack_B512<<<dim3(64), blk, 0, stream>>>(comb_W, PACK_CMB);
    wfuse_kernel<<<dim3(257), blk, 0, stream>>>(dec_embW, dec_embB, out_W, out_b, WFUSE, EBIAS);
    pack_e<<<dim3(36), blk, 0, stream>>>(WFUSE, dec_embW, PACK_E);
    pack_logits<<<dim3(24), blk, 0, stream>>>(WFUSE, dec_embW, attn_W, attn_b, dec_embB,
                                              EBIAS, PACK_BL, PACK_BL0, LB, LB0);
    pack_out<<<dim3(2), blk, 0, stream>>>(out_W, PACK_OUT);

    float*  HF[2] = {HF0, HF1};
    bf16_t* HB[2] = {HB0, HB1};
    int p = 0;

    // ---- encoder: 60 K-split gru_step2 dispatches ----
    for (int t = 0; t < LPRE; t++){
        gru_step2<<<dim3(64,4), dim3(512), 0, stream>>>(
            EMB + (size_t)t*BATCH*HD, HB[p], PACK_ENC, enc_bih, enc_bhh,
            HF[p], HF[p^1], HB[p^1], ENC_OUT + (size_t)t*BATCH*HD);
        p ^= 1;
    }
    // ---- decoder: 2 dispatches per step ----
    for (int t = 0; t < LFWD; t++){
        const bf16_t* fxt = FXB + (size_t)t*BATCH*KIN;
        dec_front<<<dim3(64), dim3(1024), 0, stream>>>(
            HB[p], fxt, ENC_OUT,
            PACK_E, t ? PACK_BL : PACK_BL0, PACK_CMB, PACK_OUT,
            t ? EBIAS : dec_embB, t ? LB : LB0, comb_b, out_b,
            t, GBUF, out);
        gru_step2<<<dim3(64,4), dim3(512), 0, stream>>>(
            GBUF, HB[p], PACK_DEC, dec_bih, dec_bhh,
            HF[p], HF[p^1], HB[p^1], DUMMY);
        p ^= 1;
    }
    final79<<<dim3(64), blk, 0, stream>>>(HF[p], out_W, out_b, out);
}